// Round 11
// baseline (473.027 us; speedup 1.0000x reference)
//
#include <hip/hip_runtime.h>

typedef __bf16 bf16x8 __attribute__((ext_vector_type(8)));
typedef float f32x4 __attribute__((ext_vector_type(4)));
typedef unsigned int u32x4 __attribute__((ext_vector_type(4)));

__device__ __forceinline__ unsigned short f2bf(float f) {
  unsigned u = __builtin_bit_cast(unsigned, f);
  u += 0x7FFFu + ((u >> 16) & 1u);
  return (unsigned short)(u >> 16);
}

// async global->LDS, 16B/lane; LDS dest = wave-uniform base + lane*16 (HW rule)
__device__ __forceinline__ void gl2lds16(const void* g, void* l) {
  __builtin_amdgcn_global_load_lds((const __attribute__((address_space(1))) void*)g,
                                   (__attribute__((address_space(3))) void*)l, 16, 0, 0);
}

__device__ __forceinline__ bf16x8 cvt8v(f32x4 a, f32x4 b) {
  bf16x8 r;
  r[0] = (__bf16)a[0]; r[1] = (__bf16)a[1]; r[2] = (__bf16)a[2]; r[3] = (__bf16)a[3];
  r[4] = (__bf16)b[0]; r[5] = (__bf16)b[1]; r[6] = (__bf16)b[2]; r[7] = (__bf16)b[3];
  return r;
}

// ---------------- W transpose: W[512 f][512 d] f32 -> Wt[512 d][512 f] bf16 --------
__global__ void transpose_cvt(const float* __restrict__ in, unsigned short* __restrict__ out) {
  __shared__ float tile[32][33];
  const int r0 = blockIdx.x * 32, c0 = blockIdx.y * 32;
  const int tx = threadIdx.x, ty = threadIdx.y;
#pragma unroll
  for (int i = 0; i < 4; ++i) tile[ty + i * 8][tx] = in[(size_t)(r0 + ty + i * 8) * 512 + c0 + tx];
  __syncthreads();
#pragma unroll
  for (int i = 0; i < 4; ++i) {
    const int cc = ty + i * 8;
    out[(size_t)(c0 + cc) * 512 + r0 + tx] = f2bf(tile[tx][cc]);
  }
}

// ---------------- counted-vmcnt ring GEMM (round-8 kernel, unchanged) --------------
template <int APITCH, int BPITCH, int NT, bool IS_Y>
__global__ __launch_bounds__(512, 1) void gemm8p(const float* __restrict__ A0,
                                                 const unsigned short* __restrict__ B0,
                                                 unsigned short* __restrict__ yT,
                                                 int* __restrict__ mask,
                                                 float* __restrict__ out) {
  __shared__ __align__(16) char lds[131072];  // 4 x (A 16KB | B 16KB)

  const int bid = blockIdx.x;
  int b, m0, n0;
  const float* Ab;
  const unsigned short* Bb;
  if constexpr (IS_Y) {
    const int mt = bid >> 1, nt = bid & 1;
    b = mt >> 4; m0 = (mt & 15) * 128; n0 = nt * 256;
    Ab = A0 + ((size_t)b * 2048 + m0) * APITCH;
    Bb = B0 + (size_t)n0 * BPITCH;
  } else {
    b = bid & 7;
    const int idx = bid >> 3;
    m0 = (idx & 15) * 128; n0 = (idx >> 4) * 256;
    Ab = A0 + ((size_t)b * 2048 + m0) * APITCH;
    Bb = B0 + ((size_t)b * 512 + n0) * BPITCH;
  }

  const int tid = threadIdx.x, w = tid >> 6, L = tid & 63;
  const int wr = w >> 2, wc = w & 3, r = L & 15, hi = L >> 4;

  const char* aSrc = (const char*)(Ab + (size_t)(w * 16 + r) * APITCH + hi * 4);
  const char* bSrc0 = (const char*)(Bb + (size_t)(w * 32 + r) * BPITCH + hi * 8);
  const char* bSrc1 = (const char*)(Bb + (size_t)(w * 32 + 16 + r) * BPITCH + hi * 8);

  int aro[4], bro[4];
#pragma unroll
  for (int mi = 0; mi < 4; ++mi)
    aro[mi] = (((wr * 4 + mi) * 2 + (hi >> 1)) << 10) + ((hi & 1) << 9) + r * 16;
#pragma unroll
  for (int ni = 0; ni < 4; ++ni) bro[ni] = 16384 + ((wc * 4 + ni) << 10) + L * 16;

  f32x4 acc[4][4] = {};
  unsigned anz[4] = {0u, 0u, 0u, 0u};

#define STAGE(SLOT, TA)                                                          \
  {                                                                              \
    char* ls = lds + (SLOT) * 32768;                                             \
    gl2lds16(aSrc + (size_t)(TA) * 128, ls + ((w * 2 + 0) << 10));               \
    gl2lds16(aSrc + (size_t)(TA) * 128 + 64, ls + ((w * 2 + 1) << 10));          \
    gl2lds16(bSrc0 + (size_t)(TA) * 64, ls + 16384 + ((w * 2 + 0) << 10));       \
    gl2lds16(bSrc1 + (size_t)(TA) * 64, ls + 16384 + ((w * 2 + 1) << 10));       \
  }

#define ORBITS(mi, lo, hh)                                                       \
  if constexpr (IS_Y) {                                                          \
    if (wc == 0) {                                                               \
      u32x4 u0 = __builtin_bit_cast(u32x4, lo), u1 = __builtin_bit_cast(u32x4, hh); \
      anz[mi] |= (u0[0] | u0[1] | u0[2] | u0[3] | u1[0] | u1[1] | u1[2] | u1[3]) & \
                 0x7fffffffu;                                                    \
    }                                                                            \
  }

  STAGE(0, 0)
  STAGE(1, 1)
  STAGE(2, 2)
  asm volatile("s_waitcnt vmcnt(8)" ::: "memory");
  __builtin_amdgcn_sched_barrier(0);
  __builtin_amdgcn_s_barrier();
  __builtin_amdgcn_sched_barrier(0);

#pragma unroll 1
  for (int t = 0; t < NT; ++t) {
    const int slot = (t + 3) & 3, cur = t & 3;
    const int ta = (t + 3 < NT) ? (t + 3) : (NT - 1);
    STAGE(slot, ta)
    __builtin_amdgcn_sched_barrier(0);
    const char* cb = lds + cur * 32768;

    bf16x8 bfr[4];
#pragma unroll
    for (int ni = 0; ni < 4; ++ni) bfr[ni] = *(const bf16x8*)(cb + bro[ni]);
    f32x4 lo0 = *(const f32x4*)(cb + aro[0]), hh0 = *(const f32x4*)(cb + aro[0] + 256);
    f32x4 lo1 = *(const f32x4*)(cb + aro[1]), hh1 = *(const f32x4*)(cb + aro[1] + 256);
    asm volatile("s_waitcnt lgkmcnt(0)" ::: "memory");
    __builtin_amdgcn_sched_barrier(0);
    ORBITS(0, lo0, hh0)
    ORBITS(1, lo1, hh1)
    bf16x8 af0 = cvt8v(lo0, hh0), af1 = cvt8v(lo1, hh1);
    __builtin_amdgcn_s_setprio(1);
#pragma unroll
    for (int ni = 0; ni < 4; ++ni)
      acc[0][ni] = __builtin_amdgcn_mfma_f32_16x16x32_bf16(af0, bfr[ni], acc[0][ni], 0, 0, 0);
#pragma unroll
    for (int ni = 0; ni < 4; ++ni)
      acc[1][ni] = __builtin_amdgcn_mfma_f32_16x16x32_bf16(af1, bfr[ni], acc[1][ni], 0, 0, 0);
    __builtin_amdgcn_s_setprio(0);

    f32x4 lo2 = *(const f32x4*)(cb + aro[2]), hh2 = *(const f32x4*)(cb + aro[2] + 256);
    f32x4 lo3 = *(const f32x4*)(cb + aro[3]), hh3 = *(const f32x4*)(cb + aro[3] + 256);
    asm volatile("s_waitcnt lgkmcnt(0)" ::: "memory");
    __builtin_amdgcn_sched_barrier(0);
    ORBITS(2, lo2, hh2)
    ORBITS(3, lo3, hh3)
    bf16x8 af2 = cvt8v(lo2, hh2), af3 = cvt8v(lo3, hh3);
    __builtin_amdgcn_s_setprio(1);
#pragma unroll
    for (int ni = 0; ni < 4; ++ni)
      acc[2][ni] = __builtin_amdgcn_mfma_f32_16x16x32_bf16(af2, bfr[ni], acc[2][ni], 0, 0, 0);
#pragma unroll
    for (int ni = 0; ni < 4; ++ni)
      acc[3][ni] = __builtin_amdgcn_mfma_f32_16x16x32_bf16(af3, bfr[ni], acc[3][ni], 0, 0, 0);
    __builtin_amdgcn_s_setprio(0);

    asm volatile("s_waitcnt vmcnt(8)" ::: "memory");
    __builtin_amdgcn_sched_barrier(0);
    __builtin_amdgcn_s_barrier();
    __builtin_amdgcn_sched_barrier(0);
  }
  asm volatile("s_waitcnt vmcnt(0)" ::: "memory");

#undef STAGE
#undef ORBITS

  if constexpr (IS_Y) {
    if (wc == 0) {
#pragma unroll
      for (int mi = 0; mi < 4; ++mi) {
        unsigned v = anz[mi];
        v |= __shfl_xor(v, 16);
        v |= __shfl_xor(v, 32);
        if (hi == 0) mask[b * 2048 + m0 + wr * 64 + mi * 16 + r] = (v != 0u) ? 1 : 0;
      }
    }
#pragma unroll
    for (int mi = 0; mi < 4; ++mi)
#pragma unroll
      for (int ni = 0; ni < 4; ++ni) {
        const int col = n0 + wc * 64 + ni * 16 + r;
        const int nrow = m0 + wr * 64 + mi * 16 + hi * 4;
        ushort4 s;
        s.x = f2bf(acc[mi][ni][0]);
        s.y = f2bf(acc[mi][ni][1]);
        s.z = f2bf(acc[mi][ni][2]);
        s.w = f2bf(acc[mi][ni][3]);
        *(ushort4*)(yT + (((size_t)b * 512 + col) << 11) + nrow) = s;
      }
  } else {
    const int* mrow = mask + b * 2048 + m0 + wr * 64;
#pragma unroll
    for (int mi = 0; mi < 4; ++mi) {
      const int4 mv = *(const int4*)(mrow + mi * 16 + hi * 4);
      const int mvv[4] = {mv.x, mv.y, mv.z, mv.w};
#pragma unroll
      for (int ni = 0; ni < 4; ++ni) {
        const int col = n0 + wc * 64 + ni * 16 + r;
        float* op = out + (size_t)(b * 2048 + m0 + wr * 64 + mi * 16 + hi * 4) * 512 + col;
#pragma unroll
        for (int rr = 0; rr < 4; ++rr) {
          float v = fmaxf(acc[mi][ni][rr], 0.0f);
          if (mvv[rr] == 0) v = 0.0f;
          op[(size_t)rr * 512] = v;
        }
      }
    }
  }
}

// ================= ABLATION PROBES (sinks alias the yT region: proven-allocated,
// consumed before probes run, never read afterward; deterministic values) ==========

// ---- p_mfma: MFMA stream + setprio + per-iter barrier, no memory. NT=256. --------
__global__ __launch_bounds__(512, 1) void p_mfma(float* __restrict__ sink) {
  const int tid = threadIdx.x;
  unsigned s0 = tid * 2654435761u + blockIdx.x * 40503u;
  u32x4 seed;
  seed[0] = s0; seed[1] = s0 ^ 0x9e3779b9u; seed[2] = s0 * 3u + 1u; seed[3] = ~s0;
  bf16x8 af[4], bfr[4];
#pragma unroll
  for (int i = 0; i < 4; ++i) {
    u32x4 t = seed; t[0] += i; t[2] ^= i * 77u;
    af[i] = __builtin_bit_cast(bf16x8, t);
    t[1] -= i; bfr[i] = __builtin_bit_cast(bf16x8, t);
  }
  f32x4 acc[4][4] = {};
#pragma unroll 1
  for (int t = 0; t < 256; ++t) {
    __builtin_amdgcn_s_setprio(1);
#pragma unroll
    for (int ni = 0; ni < 4; ++ni)
      acc[0][ni] = __builtin_amdgcn_mfma_f32_16x16x32_bf16(af[0], bfr[ni], acc[0][ni], 0, 0, 0);
#pragma unroll
    for (int ni = 0; ni < 4; ++ni)
      acc[1][ni] = __builtin_amdgcn_mfma_f32_16x16x32_bf16(af[1], bfr[ni], acc[1][ni], 0, 0, 0);
    __builtin_amdgcn_s_setprio(0);
    __builtin_amdgcn_s_setprio(1);
#pragma unroll
    for (int ni = 0; ni < 4; ++ni)
      acc[2][ni] = __builtin_amdgcn_mfma_f32_16x16x32_bf16(af[2], bfr[ni], acc[2][ni], 0, 0, 0);
#pragma unroll
    for (int ni = 0; ni < 4; ++ni)
      acc[3][ni] = __builtin_amdgcn_mfma_f32_16x16x32_bf16(af[3], bfr[ni], acc[3][ni], 0, 0, 0);
    __builtin_amdgcn_s_setprio(0);
    __builtin_amdgcn_s_barrier();
  }
  float v = 0.f;
#pragma unroll
  for (int mi = 0; mi < 4; ++mi)
#pragma unroll
    for (int ni = 0; ni < 4; ++ni) v += acc[mi][ni][0] + acc[mi][ni][3];
  sink[blockIdx.x * 512 + tid] = v;
}

// ---- p_lds: 12 ds_read_b128/iter + lgkm + barrier (R8's read pattern). NT=192. ----
__global__ __launch_bounds__(512, 1) void p_lds(float* __restrict__ sink) {
  __shared__ __align__(16) char lds[131072];
  const int tid = threadIdx.x, w = tid >> 6, L = tid & 63;
  const int wr = w >> 2, wc = w & 3, r = L & 15, hi = L >> 4;
  for (int i = tid; i < 131072 / 16; i += 512)
    *(u32x4*)(lds + i * 16) = u32x4{(unsigned)i, (unsigned)(i * 3), (unsigned)(i ^ 5), 7u};
  __syncthreads();
  int aro[4], bro[4];
#pragma unroll
  for (int mi = 0; mi < 4; ++mi)
    aro[mi] = (((wr * 4 + mi) * 2 + (hi >> 1)) << 10) + ((hi & 1) << 9) + r * 16;
#pragma unroll
  for (int ni = 0; ni < 4; ++ni) bro[ni] = 16384 + ((wc * 4 + ni) << 10) + L * 16;
  unsigned accu = 1u;
#pragma unroll 1
  for (int t = 0; t < 192; ++t) {
    const char* cb = lds + (t & 3) * 32768;
    u32x4 b0 = *(const u32x4*)(cb + bro[0]);
    u32x4 b1 = *(const u32x4*)(cb + bro[1]);
    u32x4 b2 = *(const u32x4*)(cb + bro[2]);
    u32x4 b3 = *(const u32x4*)(cb + bro[3]);
    u32x4 l0 = *(const u32x4*)(cb + aro[0]);
    u32x4 h0 = *(const u32x4*)(cb + aro[0] + 256);
    u32x4 l1 = *(const u32x4*)(cb + aro[1]);
    u32x4 h1 = *(const u32x4*)(cb + aro[1] + 256);
    asm volatile("s_waitcnt lgkmcnt(0)" ::: "memory");
    __builtin_amdgcn_sched_barrier(0);
    accu ^= b0[0] ^ b1[0] ^ b2[0] ^ b3[0] ^ l0[0] ^ h0[0] ^ l1[0] ^ h1[0];
    u32x4 l2 = *(const u32x4*)(cb + aro[2]);
    u32x4 h2 = *(const u32x4*)(cb + aro[2] + 256);
    u32x4 l3 = *(const u32x4*)(cb + aro[3]);
    u32x4 h3 = *(const u32x4*)(cb + aro[3] + 256);
    asm volatile("s_waitcnt lgkmcnt(0)" ::: "memory");
    __builtin_amdgcn_sched_barrier(0);
    accu ^= l2[0] ^ h2[0] ^ l3[0] ^ h3[0];
    __builtin_amdgcn_s_barrier();
  }
  sink[blockIdx.x * 512 + tid] = (float)accu;
}

// ---- p_stage / p_stageL2: R8's staging machinery verbatim, no compute. -----------
template <int NT, bool WRAP>
__global__ __launch_bounds__(512, 1) void p_stage(const float* __restrict__ A0,
                                                  const unsigned short* __restrict__ B0,
                                                  float* __restrict__ sink) {
  __shared__ __align__(16) char lds[131072];
  const int bid = blockIdx.x;
  const int b = bid & 7, idx = bid >> 3;
  const int m0 = (idx & 15) * 128;
  const int n0 = (idx >> 4) * 256;
  const float* Ab = A0 + ((size_t)b * 2048 + m0) * 2048;
  const unsigned short* Bb = B0 + ((size_t)b * 512 + n0) * 2048;
  const int tid = threadIdx.x, w = tid >> 6, L = tid & 63;
  const int r = L & 15, hi = L >> 4;
  const char* aSrc = (const char*)(Ab + (size_t)(w * 16 + r) * 2048 + hi * 4);
  const char* bSrc0 = (const char*)(Bb + (size_t)(w * 32 + r) * 2048 + hi * 8);
  const char* bSrc1 = (const char*)(Bb + (size_t)(w * 32 + 16 + r) * 2048 + hi * 8);

#define PSTAGE(SLOT, TA)                                                         \
  {                                                                              \
    const int taw = WRAP ? ((TA) & 7) : (TA);                                    \
    char* ls = lds + (SLOT) * 32768;                                             \
    gl2lds16(aSrc + (size_t)taw * 128, ls + ((w * 2 + 0) << 10));                \
    gl2lds16(aSrc + (size_t)taw * 128 + 64, ls + ((w * 2 + 1) << 10));           \
    gl2lds16(bSrc0 + (size_t)taw * 64, ls + 16384 + ((w * 2 + 0) << 10));        \
    gl2lds16(bSrc1 + (size_t)taw * 64, ls + 16384 + ((w * 2 + 1) << 10));        \
  }

  PSTAGE(0, 0)
  PSTAGE(1, 1)
  PSTAGE(2, 2)
  asm volatile("s_waitcnt vmcnt(8)" ::: "memory");
  __builtin_amdgcn_sched_barrier(0);
  __builtin_amdgcn_s_barrier();
  __builtin_amdgcn_sched_barrier(0);
#pragma unroll 1
  for (int t = 0; t < NT; ++t) {
    const int slot = (t + 3) & 3;
    const int ta = (t + 3 < NT) ? (t + 3) : (NT - 1);
    PSTAGE(slot, ta)
    __builtin_amdgcn_sched_barrier(0);
    asm volatile("s_waitcnt vmcnt(8)" ::: "memory");
    __builtin_amdgcn_sched_barrier(0);
    __builtin_amdgcn_s_barrier();
    __builtin_amdgcn_sched_barrier(0);
  }
  asm volatile("s_waitcnt vmcnt(0)" ::: "memory");
#undef PSTAGE
  unsigned accu = 0u;
#pragma unroll
  for (int sl = 0; sl < 4; ++sl) accu ^= *(const unsigned*)(lds + sl * 32768 + tid * 4);
  sink[blockIdx.x * 512 + tid] = (float)accu;
}

// ---------------- launch ----------------------------------------------------------
extern "C" void kernel_launch(void* const* d_in, const int* in_sizes, int n_in,
                              void* d_out, int out_size, void* d_ws, size_t ws_size,
                              hipStream_t stream) {
  const float* x = (const float*)d_in[0];   // [8][2048][512]
  const float* a = (const float*)d_in[1];   // [8][2048][2048]
  const float* wk = (const float*)d_in[2];  // [512][512]
  float* out = (float*)d_out;               // [8][2048][512]

  char* ws = (char*)d_ws;
  unsigned short* wT = (unsigned short*)ws;                 // 512 KB
  unsigned short* yT = (unsigned short*)(ws + (1u << 19));  // 16 MB
  int* mask = (int*)(ws + (1u << 19) + (16u << 20));        // 64 KB

  // probe sinks ALIAS yT (free after gemm_big consumes it; never read later).
  // 4 x 512KB inside the proven-allocated 16MB region.
  float* snk0 = (float*)(ws + (1u << 19));
  float* snk1 = (float*)(ws + (1u << 19) + (1u << 20));
  float* snk2 = (float*)(ws + (1u << 19) + (2u << 20));
  float* snk3 = (float*)(ws + (1u << 19) + (3u << 20));

  // ---- real computation (round-8 best: 99.5 us total) ----
  transpose_cvt<<<dim3(16, 16), dim3(32, 8), 0, stream>>>(wk, wT);
  gemm8p<512, 512, 16, true><<<256, 512, 0, stream>>>(x, wT, yT, mask, nullptr);
  gemm8p<2048, 2048, 64, false><<<256, 512, 0, stream>>>(a, yT, nullptr, mask, out);

  // ---- ablation probes (run AFTER yT is consumed; write scratch only) ----
  p_mfma<<<256, 512, 0, stream>>>(snk0);
  p_lds<<<256, 512, 0, stream>>>(snk1);
  p_stage<192, true><<<256, 512, 0, stream>>>(a, yT, snk2);   // cache-hot mechanism probe
  p_stage<64, false><<<256, 512, 0, stream>>>(a, yT, snk3);   // real-footprint probe
}

// Round 14
// 113.404 us; speedup vs baseline: 4.1712x; 4.1712x over previous
//
#include <hip/hip_runtime.h>

typedef __bf16 bf16x8 __attribute__((ext_vector_type(8)));
typedef float f32x4 __attribute__((ext_vector_type(4)));
typedef unsigned int u32x4 __attribute__((ext_vector_type(4)));

__device__ __forceinline__ unsigned short f2bf(float f) {
  unsigned u = __builtin_bit_cast(unsigned, f);
  u += 0x7FFFu + ((u >> 16) & 1u);
  return (unsigned short)(u >> 16);
}

// async global->LDS, 16B/lane; LDS dest = wave-uniform base + lane*16 (HW rule)
__device__ __forceinline__ void gl2lds16(const void* g, void* l) {
  __builtin_amdgcn_global_load_lds((const __attribute__((address_space(1))) void*)g,
                                   (__attribute__((address_space(3))) void*)l, 16, 0, 0);
}

__device__ __forceinline__ bf16x8 cvt8v(f32x4 a, f32x4 b) {
  bf16x8 r;
  r[0] = (__bf16)a[0]; r[1] = (__bf16)a[1]; r[2] = (__bf16)a[2]; r[3] = (__bf16)a[3];
  r[4] = (__bf16)b[0]; r[5] = (__bf16)b[1]; r[6] = (__bf16)b[2]; r[7] = (__bf16)b[3];
  return r;
}

// ---------------- W transpose: W[512 f][512 d] f32 -> Wt[512 d][512 f] bf16 --------
__global__ void transpose_cvt(const float* __restrict__ in, unsigned short* __restrict__ out) {
  __shared__ float tile[32][33];
  const int r0 = blockIdx.x * 32, c0 = blockIdx.y * 32;
  const int tx = threadIdx.x, ty = threadIdx.y;
#pragma unroll
  for (int i = 0; i < 4; ++i) tile[ty + i * 8][tx] = in[(size_t)(r0 + ty + i * 8) * 512 + c0 + tx];
  __syncthreads();
#pragma unroll
  for (int i = 0; i < 4; ++i) {
    const int cc = ty + i * 8;
    out[(size_t)(c0 + cc) * 512 + r0 + tx] = f2bf(tile[tx][cc]);
  }
}

// ---------------- gemm_y (round-8 proven, unchanged): yT = (x@W)^T + mask ----------
__global__ __launch_bounds__(512, 1) void gemm_y(const float* __restrict__ A0,
                                                 const unsigned short* __restrict__ B0,
                                                 unsigned short* __restrict__ yT,
                                                 int* __restrict__ mask) {
  constexpr int APITCH = 512, BPITCH = 512, NT = 16;
  __shared__ __align__(16) char lds[131072];
  const int bid = blockIdx.x;
  const int mt = bid >> 1, nt = bid & 1;
  const int b = mt >> 4, m0 = (mt & 15) * 128, n0 = nt * 256;
  const float* Ab = A0 + ((size_t)b * 2048 + m0) * APITCH;
  const unsigned short* Bb = B0 + (size_t)n0 * BPITCH;

  const int tid = threadIdx.x, w = tid >> 6, L = tid & 63;
  const int wr = w >> 2, wc = w & 3, r = L & 15, hi = L >> 4;

  const char* aSrc = (const char*)(Ab + (size_t)(w * 16 + r) * APITCH + hi * 4);
  const char* bSrc0 = (const char*)(Bb + (size_t)(w * 32 + r) * BPITCH + hi * 8);
  const char* bSrc1 = (const char*)(Bb + (size_t)(w * 32 + 16 + r) * BPITCH + hi * 8);

  int aro[4], bro[4];
#pragma unroll
  for (int mi = 0; mi < 4; ++mi)
    aro[mi] = (((wr * 4 + mi) * 2 + (hi >> 1)) << 10) + ((hi & 1) << 9) + r * 16;
#pragma unroll
  for (int ni = 0; ni < 4; ++ni) bro[ni] = 16384 + ((wc * 4 + ni) << 10) + L * 16;

  f32x4 acc[4][4] = {};
  unsigned anz[4] = {0u, 0u, 0u, 0u};

#define STAGE(SLOT, TA)                                                          \
  {                                                                              \
    char* ls = lds + (SLOT) * 32768;                                             \
    gl2lds16(aSrc + (size_t)(TA) * 128, ls + ((w * 2 + 0) << 10));               \
    gl2lds16(aSrc + (size_t)(TA) * 128 + 64, ls + ((w * 2 + 1) << 10));          \
    gl2lds16(bSrc0 + (size_t)(TA) * 64, ls + 16384 + ((w * 2 + 0) << 10));       \
    gl2lds16(bSrc1 + (size_t)(TA) * 64, ls + 16384 + ((w * 2 + 1) << 10));       \
  }

  STAGE(0, 0)
  STAGE(1, 1)
  STAGE(2, 2)
  asm volatile("s_waitcnt vmcnt(8)" ::: "memory");
  __builtin_amdgcn_sched_barrier(0);
  __builtin_amdgcn_s_barrier();
  __builtin_amdgcn_sched_barrier(0);

#pragma unroll 1
  for (int t = 0; t < NT; ++t) {
    const int slot = (t + 3) & 3, cur = t & 3;
    const int ta = (t + 3 < NT) ? (t + 3) : (NT - 1);
    STAGE(slot, ta)
    __builtin_amdgcn_sched_barrier(0);
    const char* cb = lds + cur * 32768;

    bf16x8 bfr[4];
#pragma unroll
    for (int ni = 0; ni < 4; ++ni) bfr[ni] = *(const bf16x8*)(cb + bro[ni]);
    f32x4 lo0 = *(const f32x4*)(cb + aro[0]), hh0 = *(const f32x4*)(cb + aro[0] + 256);
    f32x4 lo1 = *(const f32x4*)(cb + aro[1]), hh1 = *(const f32x4*)(cb + aro[1] + 256);
    asm volatile("s_waitcnt lgkmcnt(0)" ::: "memory");
    __builtin_amdgcn_sched_barrier(0);
    if (wc == 0) {
      u32x4 u0 = __builtin_bit_cast(u32x4, lo0), u1 = __builtin_bit_cast(u32x4, hh0);
      anz[0] |= (u0[0] | u0[1] | u0[2] | u0[3] | u1[0] | u1[1] | u1[2] | u1[3]) & 0x7fffffffu;
      u32x4 v0 = __builtin_bit_cast(u32x4, lo1), v1 = __builtin_bit_cast(u32x4, hh1);
      anz[1] |= (v0[0] | v0[1] | v0[2] | v0[3] | v1[0] | v1[1] | v1[2] | v1[3]) & 0x7fffffffu;
    }
    bf16x8 af0 = cvt8v(lo0, hh0), af1 = cvt8v(lo1, hh1);
    __builtin_amdgcn_s_setprio(1);
#pragma unroll
    for (int ni = 0; ni < 4; ++ni)
      acc[0][ni] = __builtin_amdgcn_mfma_f32_16x16x32_bf16(af0, bfr[ni], acc[0][ni], 0, 0, 0);
#pragma unroll
    for (int ni = 0; ni < 4; ++ni)
      acc[1][ni] = __builtin_amdgcn_mfma_f32_16x16x32_bf16(af1, bfr[ni], acc[1][ni], 0, 0, 0);
    __builtin_amdgcn_s_setprio(0);

    f32x4 lo2 = *(const f32x4*)(cb + aro[2]), hh2 = *(const f32x4*)(cb + aro[2] + 256);
    f32x4 lo3 = *(const f32x4*)(cb + aro[3]), hh3 = *(const f32x4*)(cb + aro[3] + 256);
    asm volatile("s_waitcnt lgkmcnt(0)" ::: "memory");
    __builtin_amdgcn_sched_barrier(0);
    if (wc == 0) {
      u32x4 u0 = __builtin_bit_cast(u32x4, lo2), u1 = __builtin_bit_cast(u32x4, hh2);
      anz[2] |= (u0[0] | u0[1] | u0[2] | u0[3] | u1[0] | u1[1] | u1[2] | u1[3]) & 0x7fffffffu;
      u32x4 v0 = __builtin_bit_cast(u32x4, lo3), v1 = __builtin_bit_cast(u32x4, hh3);
      anz[3] |= (v0[0] | v0[1] | v0[2] | v0[3] | v1[0] | v1[1] | v1[2] | v1[3]) & 0x7fffffffu;
    }
    bf16x8 af2 = cvt8v(lo2, hh2), af3 = cvt8v(lo3, hh3);
    __builtin_amdgcn_s_setprio(1);
#pragma unroll
    for (int ni = 0; ni < 4; ++ni)
      acc[2][ni] = __builtin_amdgcn_mfma_f32_16x16x32_bf16(af2, bfr[ni], acc[2][ni], 0, 0, 0);
#pragma unroll
    for (int ni = 0; ni < 4; ++ni)
      acc[3][ni] = __builtin_amdgcn_mfma_f32_16x16x32_bf16(af3, bfr[ni], acc[3][ni], 0, 0, 0);
    __builtin_amdgcn_s_setprio(0);

    asm volatile("s_waitcnt vmcnt(8)" ::: "memory");
    __builtin_amdgcn_sched_barrier(0);
    __builtin_amdgcn_s_barrier();
    __builtin_amdgcn_sched_barrier(0);
  }
  asm volatile("s_waitcnt vmcnt(0)" ::: "memory");
#undef STAGE

  if (wc == 0) {
#pragma unroll
    for (int mi = 0; mi < 4; ++mi) {
      unsigned v = anz[mi];
      v |= __shfl_xor(v, 16);
      v |= __shfl_xor(v, 32);
      if (hi == 0) mask[b * 2048 + m0 + wr * 64 + mi * 16 + r] = (v != 0u) ? 1 : 0;
    }
  }
#pragma unroll
  for (int mi = 0; mi < 4; ++mi)
#pragma unroll
    for (int ni = 0; ni < 4; ++ni) {
      const int col = n0 + wc * 64 + ni * 16 + r;
      const int nrow = m0 + wr * 64 + mi * 16 + hi * 4;
      ushort4 s;
      s.x = f2bf(acc[mi][ni][0]);
      s.y = f2bf(acc[mi][ni][1]);
      s.z = f2bf(acc[mi][ni][2]);
      s.w = f2bf(acc[mi][ni][3]);
      *(ushort4*)(yT + (((size_t)b * 512 + col) << 11) + nrow) = s;
    }
}

// ---------------- gemm_big: out = relu(a @ y) * mask -------------------------------
// BM=64 x BN=512 (full N): A read ONCE from L3 (134 MB total, the measured 3 TB/s
// binder); B = full yT[b] (2 MB, XCD-pinned L2). BK=32, NT=64. 8 waves (wr2 x wc4),
// wave tile 32x128, acc[2][8]. PURE global_load_lds staging (no asm reg loads):
// ring-3 x 40KB slot (A 8KB frag-ordered fp32 | B 32KB frag-ordered bf16), stage 2
// ahead, 5 glds/wave/iter (1 A + 4 B). Per iter (R8's proven WAR-safe order):
// STAGE(t+2) -> ds_read(t)+lgkm+MFMA -> vmcnt(5) [tile t+1 resident, t+2 in
// flight] -> s_barrier. The memory pipe never drains.
template <int APITCH, int BPITCH, int NT>
__global__ __launch_bounds__(512, 1) void gemm_big2(const float* __restrict__ A0,
                                                    const unsigned short* __restrict__ B0,
                                                    const int* __restrict__ mask,
                                                    float* __restrict__ out) {
  __shared__ __align__(16) char lds[122880];  // 3 slots x 40960

  const int bid = blockIdx.x;
  const int b = bid & 7, mt = bid >> 3;  // batch -> XCD pin for yT[b]
  const int m0 = mt * 64;
  const float* Ab = A0 + ((size_t)b * 2048 + m0) * APITCH;
  const unsigned short* Bb = B0 + (size_t)b * 512 * BPITCH;

  const int tid = threadIdx.x, w = tid >> 6, L = tid & 63;
  const int wr = w >> 2, wc = w & 3, r = L & 15, hi = L >> 4;

  // A staging (1 glds/wave): wave w covers rows (w>>1)*16 + r, k-half (w&1),
  // k-chunk hi (4 floats). Dest region = slot + (w<<10) (rg*2+h == w).
  const char* aSrc =
      (const char*)(Ab + (size_t)((w >> 1) * 16 + r) * APITCH) + (w & 1) * 64 + hi * 16;

  // B staging (4 glds/wave): frag g = w*4 + j covers d-rows g*16 + r, k-bytes hi*16.
  const char* bSrc[4];
#pragma unroll
  for (int j = 0; j < 4; ++j)
    bSrc[j] = (const char*)(Bb + (size_t)((w * 4 + j) * 16 + r) * BPITCH) + hi * 16;

  // A frag read offsets (within slot): rg = wr*2 + mi
  int aro[2];
#pragma unroll
  for (int mi = 0; mi < 2; ++mi)
    aro[mi] = (((wr * 2 + mi) * 2 + (hi >> 1)) << 10) + ((hi & 1) << 9) + r * 16;
  // B frag read offsets: frag g = wc*8 + ni at 8KB + g*1KB, lane-linear
  int bro[8];
#pragma unroll
  for (int ni = 0; ni < 8; ++ni) bro[ni] = 8192 + ((wc * 8 + ni) << 10) + L * 16;

  f32x4 acc[2][8] = {};

#define STAGE(SLOT, TA)                                                       \
  {                                                                           \
    char* ls = lds + (SLOT) * 40960;                                          \
    gl2lds16(aSrc + (size_t)(TA) * 128, ls + (w << 10));                      \
    _Pragma("unroll") for (int j = 0; j < 4; ++j)                             \
        gl2lds16(bSrc[j] + (size_t)(TA) * 64, ls + 8192 + ((w * 4 + j) << 10)); \
  }

  // prologue: tiles 0,1 staged; vmcnt(5) -> tile 0 resident (tile 1 in flight)
  STAGE(0, 0)
  STAGE(1, 1)
  asm volatile("s_waitcnt vmcnt(5)" ::: "memory");
  __builtin_amdgcn_sched_barrier(0);
  __builtin_amdgcn_s_barrier();
  __builtin_amdgcn_sched_barrier(0);

#pragma unroll 1
  for (int t = 0; t < NT; ++t) {
    // stage tile t+2 into slot (t+2)%3 (holds tile t-1: consumed before the
    // barrier that ended iter t-1). Tail: clamp data index; slot never read again.
    const int slot = (t + 2) % 3;
    const int ta = (t + 2 < NT) ? (t + 2) : (NT - 1);
    STAGE(slot, ta)
    __builtin_amdgcn_sched_barrier(0);

    const char* cb = lds + (t % 3) * 40960;
    bf16x8 bfr[8];
#pragma unroll
    for (int ni = 0; ni < 8; ++ni) bfr[ni] = *(const bf16x8*)(cb + bro[ni]);
    f32x4 lo0 = *(const f32x4*)(cb + aro[0]), hh0 = *(const f32x4*)(cb + aro[0] + 256);
    f32x4 lo1 = *(const f32x4*)(cb + aro[1]), hh1 = *(const f32x4*)(cb + aro[1] + 256);
    asm volatile("s_waitcnt lgkmcnt(0)" ::: "memory");
    __builtin_amdgcn_sched_barrier(0);
    bf16x8 af0 = cvt8v(lo0, hh0), af1 = cvt8v(lo1, hh1);
    __builtin_amdgcn_s_setprio(1);
#pragma unroll
    for (int ni = 0; ni < 8; ++ni)
      acc[0][ni] = __builtin_amdgcn_mfma_f32_16x16x32_bf16(af0, bfr[ni], acc[0][ni], 0, 0, 0);
#pragma unroll
    for (int ni = 0; ni < 8; ++ni)
      acc[1][ni] = __builtin_amdgcn_mfma_f32_16x16x32_bf16(af1, bfr[ni], acc[1][ni], 0, 0, 0);
    __builtin_amdgcn_s_setprio(0);

    // retire tile t+1's 5 ops (tile t+2's 5 stay in flight) -> barrier
    asm volatile("s_waitcnt vmcnt(5)" ::: "memory");
    __builtin_amdgcn_sched_barrier(0);
    __builtin_amdgcn_s_barrier();
    __builtin_amdgcn_sched_barrier(0);
  }
  asm volatile("s_waitcnt vmcnt(0)" ::: "memory");
#undef STAGE

  // epilogue: relu + row mask + fp32 store
  const int* mrow = mask + b * 2048 + m0 + wr * 32;
#pragma unroll
  for (int mi = 0; mi < 2; ++mi) {
    const int4 mv = *(const int4*)(mrow + mi * 16 + hi * 4);
    const int mvv[4] = {mv.x, mv.y, mv.z, mv.w};
#pragma unroll
    for (int ni = 0; ni < 8; ++ni) {
      const int col = wc * 128 + ni * 16 + r;
      float* op = out + (size_t)(b * 2048 + m0 + wr * 32 + mi * 16 + hi * 4) * 512 + col;
#pragma unroll
      for (int rr = 0; rr < 4; ++rr) {
        float v = fmaxf(acc[mi][ni][rr], 0.0f);
        if (mvv[rr] == 0) v = 0.0f;
        op[(size_t)rr * 512] = v;
      }
    }
  }
}

// ---------------- launch ----------------------------------------------------------
extern "C" void kernel_launch(void* const* d_in, const int* in_sizes, int n_in,
                              void* d_out, int out_size, void* d_ws, size_t ws_size,
                              hipStream_t stream) {
  const float* x = (const float*)d_in[0];   // [8][2048][512]
  const float* a = (const float*)d_in[1];   // [8][2048][2048]
  const float* wk = (const float*)d_in[2];  // [512][512]
  float* out = (float*)d_out;               // [8][2048][512]

  char* ws = (char*)d_ws;
  unsigned short* wT = (unsigned short*)ws;                 // 512 KB
  unsigned short* yT = (unsigned short*)(ws + (1u << 19));  // 16 MB
  int* mask = (int*)(ws + (1u << 19) + (16u << 20));        // 64 KB

  transpose_cvt<<<dim3(16, 16), dim3(32, 8), 0, stream>>>(wk, wT);
  // y^T = (x @ W)^T (bf16) + exact row mask.  M_flat=16384, N=512, K=512.
  gemm_y<<<256, 512, 0, stream>>>(x, wT, yT, mask);
  // out = relu(a @ y) * mask.  Per batch M=2048 (BM=64), N=512 (full), K=2048.
  gemm_big2<2048, 2048, 64><<<256, 512, 0, stream>>>(a, yT, mask, out);
}